// Round 9
// baseline (415.263 us; speedup 1.0000x reference)
//
#include <hip/hip_runtime.h>

// ---------------------------------------------------------------------------
// Self-attention, B=4 S=4096 D=DOUT=1024, fp32 in/out.
// scores = x (Wq Wk^T / 32) x^T  -> t = x*M ; S = t x^T  (accuracy trick)
// Round 9: gemm256 switches to mfma_f32_32x32x16_bf16 (half the MFMA
// instruction count, measured-faster pipe), keeping round-6's best schedule
// (4-phase/K-tile, 1 barrier/phase, vmcnt(4)@PH3, hoisted addressing).
// A/B operand: lane l -> row l&31, k=(l>>5)*8+j. C/D: col=lane&31,
// row=(reg&3)+8*(reg>>2)+4*(lane>>5)  [m74/m101-verified].
// ---------------------------------------------------------------------------

typedef unsigned short ushort_t;
typedef __attribute__((ext_vector_type(8)))  short    bf16x8;
typedef __attribute__((ext_vector_type(4)))  float    f32x4;
typedef __attribute__((ext_vector_type(16))) float    f32x16;
typedef __attribute__((ext_vector_type(4)))  unsigned int u32x4;
typedef __attribute__((ext_vector_type(4)))  unsigned short u16x4;

__device__ __forceinline__ unsigned short f2bf(float f) {
  unsigned u = __float_as_uint(f);
  return (unsigned short)((u + 0x7FFFu + ((u >> 16) & 1u)) >> 16);
}
__device__ __forceinline__ float bf2f(unsigned short h) {
  return __uint_as_float((unsigned)h << 16);
}

#define GLOAD16(gsrc, ldst)                                                        \
  __builtin_amdgcn_global_load_lds(                                                \
      (const __attribute__((address_space(1))) void*)(gsrc),                       \
      (__attribute__((address_space(3))) void*)(ldst), 16, 0, 0)
#define WAITVM(N) asm volatile("s_waitcnt vmcnt(" #N ")" ::: "memory")
#define SCHED0()  __builtin_amdgcn_sched_barrier(0)
#define BARRIER() __builtin_amdgcn_s_barrier()

// ---------------------------------------------------------------------------
__global__ __launch_bounds__(256) void cast_bf16_kernel(const float* __restrict__ in,
                                                        ushort_t* __restrict__ out) {
  long i = (long)blockIdx.x * 256 + threadIdx.x;
  const f32x4* p = (const f32x4*)(in + i * 8);
  f32x4 a = p[0], b = p[1];
  u32x4 o;
  o.x = (unsigned)f2bf(a[0]) | ((unsigned)f2bf(a[1]) << 16);
  o.y = (unsigned)f2bf(a[2]) | ((unsigned)f2bf(a[3]) << 16);
  o.z = (unsigned)f2bf(b[0]) | ((unsigned)f2bf(b[1]) << 16);
  o.w = (unsigned)f2bf(b[2]) | ((unsigned)f2bf(b[3]) << 16);
  ((u32x4*)out)[i] = o;
}

__global__ __launch_bounds__(256) void prep_weights_kernel(const float* __restrict__ kern,
                                                           ushort_t* __restrict__ wk,
                                                           ushort_t* __restrict__ wq,
                                                           ushort_t* __restrict__ wvt) {
  int idx = blockIdx.x * 256 + threadIdx.x;
  wk[idx] = f2bf(kern[idx]);
  wq[idx] = f2bf(kern[1048576 + idx] * 0.03125f);
  int e = idx >> 10, d = idx & 1023;
  wvt[idx] = f2bf(kern[2097152 + d * 1024 + e]);
}

// ---------------------------------------------------------------------------
// 128^2-tile GEMM (kept for the tiny Mt GEMM + low-ws fallback)
template <int OUT_BF16>
__global__ __launch_bounds__(256) void gemm_bt(const ushort_t* __restrict__ A, long lda, long batchA,
                                               const ushort_t* __restrict__ B, long ldb, long batchB,
                                               void* __restrict__ C, long ldc, long batchC,
                                               int K) {
  __shared__ ushort_t lA[128 * 64];
  __shared__ ushort_t lB[128 * 64];

  const int tid  = threadIdx.x;
  const int lane = tid & 63;
  const int wid  = tid >> 6;
  const int wr   = wid >> 1;
  const int wc   = wid & 1;

  const ushort_t* Ab = A + (long)blockIdx.z * batchA + (long)blockIdx.y * 128 * lda;
  const ushort_t* Bb = B + (long)blockIdx.z * batchB + (long)blockIdx.x * 128 * ldb;

  f32x4 acc[4][4] = {};

  const int nkt = K >> 6;
  for (int kt = 0; kt < nkt; ++kt) {
#pragma unroll
    for (int i = 0; i < 4; ++i) {
      int c = tid + i * 256;
      int row = c >> 3, p = c & 7;
      int sc = p ^ (row & 7);
      GLOAD16(Ab + (long)row * lda + kt * 64 + sc * 8, &lA[c * 8]);
    }
#pragma unroll
    for (int i = 0; i < 4; ++i) {
      int c = tid + i * 256;
      int row = c >> 3, p = c & 7;
      int sc = p ^ (row & 7);
      GLOAD16(Bb + (long)row * ldb + kt * 64 + sc * 8, &lB[c * 8]);
    }
    __syncthreads();

    const int lr = lane & 15, lg = lane >> 4;
#pragma unroll
    for (int kk = 0; kk < 2; ++kk) {
      bf16x8 af[4], bfr[4];
#pragma unroll
      for (int m = 0; m < 4; ++m) {
        int row = wr * 64 + m * 16 + lr;
        int cidx = kk * 4 + lg;
        af[m] = *(const bf16x8*)((const char*)lA + row * 128 + ((cidx ^ (row & 7)) << 4));
      }
#pragma unroll
      for (int n = 0; n < 4; ++n) {
        int row = wc * 64 + n * 16 + lr;
        int cidx = kk * 4 + lg;
        bfr[n] = *(const bf16x8*)((const char*)lB + row * 128 + ((cidx ^ (row & 7)) << 4));
      }
#pragma unroll
      for (int m = 0; m < 4; ++m)
#pragma unroll
        for (int n = 0; n < 4; ++n)
          acc[m][n] = __builtin_amdgcn_mfma_f32_16x16x32_bf16(af[m], bfr[n], acc[m][n], 0, 0, 0);
    }
    __syncthreads();
  }

  const long Crow0 = (long)blockIdx.y * 128 + wr * 64;
  const long Ccol0 = (long)blockIdx.x * 128 + wc * 64;
  float*     Cf = (float*)C + (long)blockIdx.z * batchC;
  ushort_t*  Cb = (ushort_t*)C + (long)blockIdx.z * batchC;
#pragma unroll
  for (int m = 0; m < 4; ++m) {
    long r0 = Crow0 + m * 16 + ((lane >> 4) << 2);
#pragma unroll
    for (int n = 0; n < 4; ++n) {
      long cc = Ccol0 + n * 16 + (lane & 15);
#pragma unroll
      for (int j = 0; j < 4; ++j) {
        float val = acc[m][n][j];
        if (OUT_BF16) Cb[(r0 + j) * ldc + cc] = f2bf(val);
        else          Cf[(r0 + j) * ldc + cc] = val;
      }
    }
  }
}

// ---------------------------------------------------------------------------
// 256x256-tile GEMM, BK=64, 512 threads (8 waves, 2Mx4N), 4-phase/K-tile,
// ONE barrier per phase, vmcnt(4) once per K-tile at PH3, hoisted addressing.
// MFMA = 32x32x16 bf16: per wave 4 m-tiles x 2 n-tiles of 32x32; phase q =
// m-tile q x full N x full BK (8 MFMA). Staging identical to rounds 5-8.
template <int OUT_BF16>
__global__ __launch_bounds__(512, 1) void gemm256(
    const ushort_t* __restrict__ A, long lda, long batchA,
    const ushort_t* __restrict__ B, long ldb, long batchB,
    void* __restrict__ C, long ldc, long batchC,
    int K, int tx, int ty) {
  __shared__ ushort_t lds[2][2][16384];   // [dbuf][A=0/B=1][256 rows x 64 cols]

  const int nblk = gridDim.x;
  int f = blockIdx.x;
  f = (f & 7) * (nblk >> 3) + (f >> 3);   // XCD-aware swizzle (nblk % 8 == 0)
  const int txy = tx * ty;
  const int bz = f / txy;
  int r = f - bz * txy;
  const int by = r / tx;
  const int bx = r - by * tx;

  const int tid  = threadIdx.x;
  const int lane = tid & 63;
  const int wid  = tid >> 6;
  const int wr   = wid >> 2;              // 0..1 (M half, 128 rows)
  const int wc   = wid & 3;               // 0..3 (N quarter, 64 cols)
  const int l31  = lane & 31;
  const int h    = lane >> 5;             // k-half selector for 32x32x16

  // ---- ds_read lane bases (32x32 fetch): byte = base + q*4096 + off[c] ----
  // row = [tile-group] + l31 ; chunk = 2c + h ; swizzle ^ (row&7) = ^ (l31&7)
  const int baseA = wr * 16384 + l31 * 128;
  const int baseB = 32768 + wc * 8192 + l31 * 128;
  int offc[4];
#pragma unroll
  for (int c = 0; c < 4; ++c) offc[c] = ((2 * c + h) ^ (l31 & 7)) << 4;

  // ---- stage addressing: 2 advancing pointers + uniform offsets ----
  const int r7    = tid >> 3;                     // A row (alpha0,h0)
  const int pch   = tid & 7;
  const int rowB0 = (r7 & 31) | ((r7 & 32) << 1); // B row (beta0,h0)
  const long lda2 = lda * 2, ldb2 = ldb * 2;      // row stride in bytes
  const ushort_t* Abp = A + (long)bz * batchA + (long)by * 256 * lda;
  const ushort_t* Bbp = B + (long)bz * batchB + (long)bx * 256 * ldb;
  const char* gA = (const char*)(Abp + (long)r7 * lda + (pch ^ (r7 & 7)) * 8);
  const char* gB = (const char*)(Bbp + (long)rowB0 * ldb + (pch ^ (rowB0 & 7)) * 8);
  const int dA0 = r7 * 128 + pch * 16;            // LDS dest base (op A)
  const int dB0 = 32768 + rowB0 * 128 + pch * 16; // LDS dest base (op B)
  char* ldsc = (char*)&lds[0][0][0];

  // uniform per-variant source offsets (bytes): rowDelta*ld2 + tileDelta*128
  const long aP0 = 64 * lda2 + 128,  aP1 = 192 * lda2 + 128;   // alpha1 h0/h1 @t+1
  const long aP2 = 256,              aP2b = 128 * lda2 + 256;  // alpha0 h0/h1 @t+2
  const long bP0 = 32 * ldb2 + 128,  bP1 = 160 * ldb2 + 128;   // beta1  h0/h1 @t+1
  const long bP3 = 256,              bP3b = 128 * ldb2 + 256;  // beta0  h0/h1 @t+2

  f32x16 acc[4][2] = {};
  bf16x8 afr[4];       // current m-tile fragments (4 k-steps)
  bf16x8 bfr[2][4];    // full-N fragments (held across the K-tile)

  auto gld = [&](const char* src, int dst) {
    __builtin_amdgcn_global_load_lds((const __attribute__((address_space(1))) void*)src,
                                     (__attribute__((address_space(3))) void*)(ldsc + dst),
                                     16, 0, 0);
  };
  auto readAq = [&](const char* lc, int q) {
#pragma unroll
    for (int c = 0; c < 4; ++c)
      afr[c] = *(const bf16x8*)(lc + baseA + q * 4096 + offc[c]);
  };
  auto readB = [&](const char* lc) {
#pragma unroll
    for (int nt = 0; nt < 2; ++nt)
#pragma unroll
      for (int c = 0; c < 4; ++c)
        bfr[nt][c] = *(const bf16x8*)(lc + baseB + nt * 4096 + offc[c]);
  };
  auto mfma8q = [&](int q) {
    __builtin_amdgcn_s_setprio(1);
#pragma unroll
    for (int c = 0; c < 4; ++c)
#pragma unroll
      for (int nt = 0; nt < 2; ++nt)
        acc[q][nt] = __builtin_amdgcn_mfma_f32_32x32x16_bf16(
            afr[c], bfr[nt][c], acc[q][nt], 0, 0, 0);
    __builtin_amdgcn_s_setprio(0);
  };

  const int nkt = K >> 6;                 // >= 16 for all our shapes
  // prologue: tile0 full -> buf0 (first 8 issues), tile1 1st halves -> buf1
  gld(gA, dA0);                    gld(gA + 128 * lda2, dA0 + 16384);
  gld(gB, dB0);                    gld(gB + 128 * ldb2, dB0 + 16384);
  gld(gA + 64 * lda2, dA0 + 8192); gld(gA + 192 * lda2, dA0 + 24576);
  gld(gB + 32 * ldb2, dB0 + 4096); gld(gB + 160 * ldb2, dB0 + 20480);
  gld(gA + 128, 65536 + dA0);            gld(gA + 128 * lda2 + 128, 65536 + dA0 + 16384);
  gld(gB + 128, 65536 + dB0);            gld(gB + 128 * ldb2 + 128, 65536 + dB0 + 16384);
  WAITVM(4);                              // tile0's 8 loads landed
  BARRIER(); SCHED0();

  for (int t = 0; t < nkt - 2; ++t) {
    const int cb = t & 1;
    const char* lc = ldsc + (cb << 16);
    const int obo = (cb ^ 1) << 16, cbo = cb << 16;
    // PH0
    readB(lc);
    readAq(lc, 0);
    gld(gA + aP0, obo + dA0 + 8192);  gld(gB + bP0, obo + dB0 + 4096);
    mfma8q(0); BARRIER(); SCHED0();
    // PH1
    readAq(lc, 1);
    gld(gA + aP1, obo + dA0 + 24576); gld(gB + bP1, obo + dB0 + 20480);
    mfma8q(1); BARRIER(); SCHED0();
    // PH2
    readAq(lc, 2);
    gld(gA + aP2, cbo + dA0);         gld(gA + aP2b, cbo + dA0 + 16384);
    mfma8q(2); BARRIER(); SCHED0();
    // PH3
    readAq(lc, 3);
    gld(gB + bP3, cbo + dB0);         gld(gB + bP3b, cbo + dB0 + 16384);
    WAITVM(4);
    mfma8q(3); BARRIER(); SCHED0();
    gA += 128; gB += 128;                 // advance one K-tile (64 elem * 2B)
  }
  {                                       // t = nkt-2: stage tile nkt-1 2nd halves only
    const int cb = (nkt - 2) & 1;
    const char* lc = ldsc + (cb << 16);
    const int obo = (cb ^ 1) << 16;
    readB(lc);
    readAq(lc, 0);
    gld(gA + aP0, obo + dA0 + 8192);  gld(gB + bP0, obo + dB0 + 4096);
    mfma8q(0); BARRIER(); SCHED0();
    readAq(lc, 1);
    gld(gA + aP1, obo + dA0 + 24576); gld(gB + bP1, obo + dB0 + 20480);
    mfma8q(1); BARRIER(); SCHED0();
    readAq(lc, 2);
    mfma8q(2); BARRIER(); SCHED0();
    readAq(lc, 3);
    WAITVM(0);                            // drain: tile nkt-1 fully landed
    mfma8q(3); BARRIER(); SCHED0();
  }
  {                                       // t = nkt-1: pure compute, no hazards
    const int cb = (nkt - 1) & 1;
    const char* lc = ldsc + (cb << 16);
    readB(lc);
    readAq(lc, 0); mfma8q(0);
    readAq(lc, 1); mfma8q(1);
    readAq(lc, 2); mfma8q(2);
    readAq(lc, 3); mfma8q(3);
  }

  // epilogue: 32x32 C/D layout col=lane&31, row=(reg&3)+8*(reg>>2)+4*(lane>>5)
  const long Crow0 = (long)by * 256 + wr * 128;
  const long Ccol0 = (long)bx * 256 + wc * 64;
  float*     Cf = (float*)C + (long)bz * batchC;
  ushort_t*  Cb = (ushort_t*)C + (long)bz * batchC;
#pragma unroll
  for (int mt = 0; mt < 4; ++mt) {
#pragma unroll
    for (int nt = 0; nt < 2; ++nt) {
      long cc = Ccol0 + nt * 32 + l31;
#pragma unroll
      for (int reg = 0; reg < 16; ++reg) {
        long rr = Crow0 + mt * 32 + (reg & 3) + 8 * (reg >> 2) + 4 * h;
        float val = acc[mt][nt][reg];
        if (OUT_BF16) Cb[rr * ldc + cc] = f2bf(val);
        else          Cf[rr * ldc + cc] = val;
      }
    }
  }
}

// ---------------------------------------------------------------------------
// row softmax over 4096 fp32 scores; write normalized P bf16 to P+row*pstride
__global__ __launch_bounds__(256) void softmax_kernel(float* __restrict__ S,
                                                      ushort_t* __restrict__ P,
                                                      long pstride) {
  float* row = S + (long)blockIdx.x * 4096;
  const int tid = threadIdx.x;
  __shared__ float red[4];

  f32x4 v[4];
#pragma unroll
  for (int i = 0; i < 4; ++i) v[i] = ((const f32x4*)row)[tid + i * 256];

  float m = -1e30f;
#pragma unroll
  for (int i = 0; i < 4; ++i)
#pragma unroll
    for (int j = 0; j < 4; ++j) m = fmaxf(m, v[i][j]);
  for (int o = 32; o; o >>= 1) m = fmaxf(m, __shfl_xor(m, o));
  if ((tid & 63) == 0) red[tid >> 6] = m;
  __syncthreads();
  m = fmaxf(fmaxf(red[0], red[1]), fmaxf(red[2], red[3]));

  float p[16];
  float s = 0.f;
#pragma unroll
  for (int i = 0; i < 4; ++i)
#pragma unroll
    for (int j = 0; j < 4; ++j) {
      float e = __expf(v[i][j] - m);
      p[i * 4 + j] = e;
      s += e;
    }
  for (int o = 32; o; o >>= 1) s += __shfl_xor(s, o);
  __syncthreads();
  if ((tid & 63) == 0) red[tid >> 6] = s;
  __syncthreads();
  s = red[0] + red[1] + red[2] + red[3];
  float inv = 1.0f / s;

  u16x4* prow = (u16x4*)(P + (long)blockIdx.x * pstride);
#pragma unroll
  for (int i = 0; i < 4; ++i) {
    u16x4 o;
    o.x = f2bf(p[i * 4 + 0] * inv);
    o.y = f2bf(p[i * 4 + 1] * inv);
    o.z = f2bf(p[i * 4 + 2] * inv);
    o.w = f2bf(p[i * 4 + 3] * inv);
    prow[tid + i * 256] = o;
  }
}

// row softmax over 4096 bf16 scores, P bf16 written IN PLACE (row-local)
__global__ __launch_bounds__(256) void softmax_bf16_kernel(ushort_t* __restrict__ S) {
  u16x4* row = (u16x4*)(S + (long)blockIdx.x * 4096);
  const int tid = threadIdx.x;
  __shared__ float red[4];

  float v[16];
#pragma unroll
  for (int i = 0; i < 4; ++i) {
    u16x4 h = row[tid + i * 256];
    v[i * 4 + 0] = bf2f(h.x); v[i * 4 + 1] = bf2f(h.y);
    v[i * 4 + 2] = bf2f(h.z); v[i * 4 + 3] = bf2f(h.w);
  }

  float m = -1e30f;
#pragma unroll
  for (int i = 0; i < 16; ++i) m = fmaxf(m, v[i]);
  for (int o = 32; o; o >>= 1) m = fmaxf(m, __shfl_xor(m, o));
  if ((tid & 63) == 0) red[tid >> 6] = m;
  __syncthreads();
  m = fmaxf(fmaxf(red[0], red[1]), fmaxf(red[2], red[3]));

  float s = 0.f;
#pragma unroll
  for (int i = 0; i < 16; ++i) {
    v[i] = __expf(v[i] - m);
    s += v[i];
  }
  for (int o = 32; o; o >>= 1) s += __shfl_xor(s, o);
  __syncthreads();
  if ((tid & 63) == 0) red[tid >> 6] = s;
  __syncthreads();
  s = red[0] + red[1] + red[2] + red[3];
  float inv = 1.0f / s;

#pragma unroll
  for (int i = 0; i < 4; ++i) {
    u16x4 o;
    o.x = f2bf(v[i * 4 + 0] * inv);
    o.y = f2bf(v[i * 4 + 1] * inv);
    o.z = f2bf(v[i * 4 + 2] * inv);
    o.w = f2bf(v[i * 4 + 3] * inv);
    row[tid + i * 256] = o;
  }
}

// ---------------------------------------------------------------------------
extern "C" void kernel_launch(void* const* d_in, const int* in_sizes, int n_in,
                              void* d_out, int out_size, void* d_ws, size_t ws_size,
                              hipStream_t stream) {
  const float* x    = (const float*)d_in[0];   // [4,4096,1024]
  const float* kern = (const float*)d_in[1];   // [3,1024,1024]
  float* out = (float*)d_out;                  // [4,4096,1024]

  char* p = (char*)d_ws;
  ushort_t* xbf = (ushort_t*)p; p += 33554432;         // 16384x1024 bf16
  ushort_t* t   = (ushort_t*)p; p += 33554432;         // 16384x1024 bf16
  ushort_t* vT  = (ushort_t*)p; p += 33554432;         // 4x1024x4096 bf16
  ushort_t* wk  = (ushort_t*)p; p += 2097152;
  ushort_t* wq  = (ushort_t*)p; p += 2097152;
  ushort_t* wvt = (ushort_t*)p; p += 2097152;
  ushort_t* mt  = (ushort_t*)p; p += 2097152;
  size_t fixed = (size_t)(p - (char*)d_ws);            // 104 MiB

  cast_bf16_kernel<<<8192, 256, 0, stream>>>(x, xbf);
  prep_weights_kernel<<<4096, 256, 0, stream>>>(kern, wk, wq, wvt);
  // Mt[d',d] = sum_e Wk[d',e] * Wq_s[d,e]  (tiny; 128^2 kernel)
  gemm_bt<1><<<dim3(8, 8, 1), 256, 0, stream>>>(wk, 1024, 0, wq, 1024, 0, mt, 1024, 0, 1024);

  const size_t need4 = fixed + 4ull * 33554432;        // 4 bf16 S/P buffers
  const size_t need2 = fixed + 2ull * 33554432;        // 2 bf16 S/P buffers

  if (ws_size >= need2) {
    ushort_t* Sb = (ushort_t*)p;                       // 2 or 4 x (4096x4096 bf16)

    // t[q,d'] = sum_d x[q,d] * Mt[d',d]      grid 4x64 = 256
    gemm256<1><<<dim3(256), dim3(512), 0, stream>>>(xbf, 1024, 0, mt, 1024, 0,
                                                    t, 1024, 0, 1024, 4, 64);
    // vT[b][e,s] = sum_d WvT[e,d] * x_b[s,d]  grid 16x4x4 = 256
    gemm256<1><<<dim3(256), dim3(512), 0, stream>>>(wvt, 1024, 0,
                                                    xbf, 1024, 4194304,
                                                    vT, 4096, 4194304, 1024, 16, 4);

    const int nb_at_once = (ws_size >= need4) ? 4 : 2;
    for (int b0 = 0; b0 < 4; b0 += nb_at_once) {
      // S_b[q,k] = sum_d' t_b[q,d'] x_b[k,d']  (bf16 out), batched dispatch
      gemm256<1><<<dim3(256 * nb_at_once), dim3(512), 0, stream>>>(
          t + (long)b0 * 4194304, 1024, 4194304,
          xbf + (long)b0 * 4194304, 1024, 4194304,
          Sb, 4096, 16777216, 1024, 16, 16);
      // softmax all staged rows in one dispatch (in-place bf16 P)
      softmax_bf16_kernel<<<4096 * nb_at_once, 256, 0, stream>>>(Sb);
      // out[b][q,e] = sum_k P_b[q,k] vT_b[e,k]
      gemm256<0><<<dim3(4 * 16 * nb_at_once), dim3(512), 0, stream>>>(
          Sb, 4096, 16777216,
          vT + (long)b0 * 4194304, 4096, 4194304,
          out + (long)b0 * 4194304, 1024, 4194304, 4096, 4, 16);
    }
  } else {
    // -------- low-ws fallback (chunked, in-place packed P) --------
    float* Sbuf = (float*)p;
    long CR = 4096;
    while (CR > 256 && fixed + (size_t)CR * 4096 * 4 > ws_size) CR >>= 1;

    gemm_bt<1><<<dim3(8, 128, 1), 256, 0, stream>>>(xbf, 1024, 0, mt, 1024, 0, t, 1024, 0, 1024);
    gemm_bt<1><<<dim3(32, 8, 4), 256, 0, stream>>>(wvt, 1024, 0,
                                                   xbf, 1024, 4194304,
                                                   vT, 4096, 4194304, 1024);
    for (int b = 0; b < 4; ++b) {
      const ushort_t* xb  = xbf + (long)b * 4194304;
      const ushort_t* vTb = vT  + (long)b * 4194304;
      for (long c0 = 0; c0 < 4096; c0 += CR) {
        const ushort_t* tb = t + ((long)b * 4096 + c0) * 1024;
        gemm_bt<0><<<dim3(32, CR / 128, 1), 256, 0, stream>>>(tb, 1024, 0, xb, 1024, 0,
                                                              Sbuf, 4096, 0, 1024);
        softmax_kernel<<<CR, 256, 0, stream>>>(Sbuf, (ushort_t*)Sbuf, 8192);
        gemm_bt<0><<<dim3(8, CR / 128, 1), 256, 0, stream>>>((const ushort_t*)Sbuf, 8192, 0,
                                                             vTb, 4096, 0,
                                                             out + ((long)b * 4096 + c0) * 1024, 1024, 0,
                                                             4096);
      }
    }
  }
}

// Round 10
// 384.313 us; speedup vs baseline: 1.0805x; 1.0805x over previous
//
#include <hip/hip_runtime.h>

// ---------------------------------------------------------------------------
// Self-attention, B=4 S=4096 D=DOUT=1024, fp32 in/out.
// scores = x (Wq Wk^T / 32) x^T  -> t = x*M ; S = t x^T  (accuracy trick)
// Round 10: exact revert to round-6 (best measured: 385.2us).
// gemm256: 256^2 tile, BK=64, 8 waves, 4-phase/K-tile, 1 barrier/phase,
// vmcnt(4) once per K-tile, fully hoisted addressing, 16x16x32 MFMA
// (conflict-free swizzle: consecutive 8-lane groups tile all 8 slots).
// ---------------------------------------------------------------------------

typedef unsigned short ushort_t;
typedef __attribute__((ext_vector_type(8))) short     bf16x8;
typedef __attribute__((ext_vector_type(4))) float     f32x4;
typedef __attribute__((ext_vector_type(4))) unsigned int u32x4;
typedef __attribute__((ext_vector_type(4))) unsigned short u16x4;

__device__ __forceinline__ unsigned short f2bf(float f) {
  unsigned u = __float_as_uint(f);
  return (unsigned short)((u + 0x7FFFu + ((u >> 16) & 1u)) >> 16);
}
__device__ __forceinline__ float bf2f(unsigned short h) {
  return __uint_as_float((unsigned)h << 16);
}

#define GLOAD16(gsrc, ldst)                                                        \
  __builtin_amdgcn_global_load_lds(                                                \
      (const __attribute__((address_space(1))) void*)(gsrc),                       \
      (__attribute__((address_space(3))) void*)(ldst), 16, 0, 0)
#define WAITVM(N) asm volatile("s_waitcnt vmcnt(" #N ")" ::: "memory")
#define SCHED0()  __builtin_amdgcn_sched_barrier(0)
#define BARRIER() __builtin_amdgcn_s_barrier()

// ---------------------------------------------------------------------------
__global__ __launch_bounds__(256) void cast_bf16_kernel(const float* __restrict__ in,
                                                        ushort_t* __restrict__ out) {
  long i = (long)blockIdx.x * 256 + threadIdx.x;
  const f32x4* p = (const f32x4*)(in + i * 8);
  f32x4 a = p[0], b = p[1];
  u32x4 o;
  o.x = (unsigned)f2bf(a[0]) | ((unsigned)f2bf(a[1]) << 16);
  o.y = (unsigned)f2bf(a[2]) | ((unsigned)f2bf(a[3]) << 16);
  o.z = (unsigned)f2bf(b[0]) | ((unsigned)f2bf(b[1]) << 16);
  o.w = (unsigned)f2bf(b[2]) | ((unsigned)f2bf(b[3]) << 16);
  ((u32x4*)out)[i] = o;
}

__global__ __launch_bounds__(256) void prep_weights_kernel(const float* __restrict__ kern,
                                                           ushort_t* __restrict__ wk,
                                                           ushort_t* __restrict__ wq,
                                                           ushort_t* __restrict__ wvt) {
  int idx = blockIdx.x * 256 + threadIdx.x;
  wk[idx] = f2bf(kern[idx]);
  wq[idx] = f2bf(kern[1048576 + idx] * 0.03125f);
  int e = idx >> 10, d = idx & 1023;
  wvt[idx] = f2bf(kern[2097152 + d * 1024 + e]);
}

// ---------------------------------------------------------------------------
// 128^2-tile GEMM (kept for the tiny Mt GEMM + low-ws fallback)
template <int OUT_BF16>
__global__ __launch_bounds__(256) void gemm_bt(const ushort_t* __restrict__ A, long lda, long batchA,
                                               const ushort_t* __restrict__ B, long ldb, long batchB,
                                               void* __restrict__ C, long ldc, long batchC,
                                               int K) {
  __shared__ ushort_t lA[128 * 64];
  __shared__ ushort_t lB[128 * 64];

  const int tid  = threadIdx.x;
  const int lane = tid & 63;
  const int wid  = tid >> 6;
  const int wr   = wid >> 1;
  const int wc   = wid & 1;

  const ushort_t* Ab = A + (long)blockIdx.z * batchA + (long)blockIdx.y * 128 * lda;
  const ushort_t* Bb = B + (long)blockIdx.z * batchB + (long)blockIdx.x * 128 * ldb;

  f32x4 acc[4][4] = {};

  const int nkt = K >> 6;
  for (int kt = 0; kt < nkt; ++kt) {
#pragma unroll
    for (int i = 0; i < 4; ++i) {
      int c = tid + i * 256;
      int row = c >> 3, p = c & 7;
      int sc = p ^ (row & 7);
      GLOAD16(Ab + (long)row * lda + kt * 64 + sc * 8, &lA[c * 8]);
    }
#pragma unroll
    for (int i = 0; i < 4; ++i) {
      int c = tid + i * 256;
      int row = c >> 3, p = c & 7;
      int sc = p ^ (row & 7);
      GLOAD16(Bb + (long)row * ldb + kt * 64 + sc * 8, &lB[c * 8]);
    }
    __syncthreads();

    const int lr = lane & 15, lg = lane >> 4;
#pragma unroll
    for (int kk = 0; kk < 2; ++kk) {
      bf16x8 af[4], bfr[4];
#pragma unroll
      for (int m = 0; m < 4; ++m) {
        int row = wr * 64 + m * 16 + lr;
        int cidx = kk * 4 + lg;
        af[m] = *(const bf16x8*)((const char*)lA + row * 128 + ((cidx ^ (row & 7)) << 4));
      }
#pragma unroll
      for (int n = 0; n < 4; ++n) {
        int row = wc * 64 + n * 16 + lr;
        int cidx = kk * 4 + lg;
        bfr[n] = *(const bf16x8*)((const char*)lB + row * 128 + ((cidx ^ (row & 7)) << 4));
      }
#pragma unroll
      for (int m = 0; m < 4; ++m)
#pragma unroll
        for (int n = 0; n < 4; ++n)
          acc[m][n] = __builtin_amdgcn_mfma_f32_16x16x32_bf16(af[m], bfr[n], acc[m][n], 0, 0, 0);
    }
    __syncthreads();
  }

  const long Crow0 = (long)blockIdx.y * 128 + wr * 64;
  const long Ccol0 = (long)blockIdx.x * 128 + wc * 64;
  float*     Cf = (float*)C + (long)blockIdx.z * batchC;
  ushort_t*  Cb = (ushort_t*)C + (long)blockIdx.z * batchC;
#pragma unroll
  for (int m = 0; m < 4; ++m) {
    long r0 = Crow0 + m * 16 + ((lane >> 4) << 2);
#pragma unroll
    for (int n = 0; n < 4; ++n) {
      long cc = Ccol0 + n * 16 + (lane & 15);
#pragma unroll
      for (int j = 0; j < 4; ++j) {
        float val = acc[m][n][j];
        if (OUT_BF16) Cb[(r0 + j) * ldc + cc] = f2bf(val);
        else          Cf[(r0 + j) * ldc + cc] = val;
      }
    }
  }
}

// ---------------------------------------------------------------------------
// 256x256-tile GEMM, BK=64, 512 threads (8 waves, 2Mx4N), 4-phase/K-tile,
// ONE barrier per phase, vmcnt(4) once per K-tile at PH3.
// All addressing hoisted: ds_read = 4 lane-base VGPRs + imm offsets;
// stage src = 2 pointer VGPRs (+128B/tile) + uniform offsets; stage dst =
// 2 per-thread consts + compile-time deltas + buf bit.
// Schedule/ledger verified passing (rounds 5-8): PH0/PH1 stage tile t+1 2nd
// halves -> ob; PH2/PH3 stage tile t+2 1st halves -> cb; reads of a staged
// region always retired >= 1 end-barrier before its overwrite; vmcnt(4)@PH3
// + barrier guarantees tile t+1 fully landed before its PH0 reads.
template <int OUT_BF16>
__global__ __launch_bounds__(512, 1) void gemm256(
    const ushort_t* __restrict__ A, long lda, long batchA,
    const ushort_t* __restrict__ B, long ldb, long batchB,
    void* __restrict__ C, long ldc, long batchC,
    int K, int tx, int ty) {
  __shared__ ushort_t lds[2][2][16384];   // [dbuf][A=0/B=1][256 rows x 64 cols]

  const int nblk = gridDim.x;
  int f = blockIdx.x;
  f = (f & 7) * (nblk >> 3) + (f >> 3);   // XCD-aware swizzle (nblk % 8 == 0)
  const int txy = tx * ty;
  const int bz = f / txy;
  int r = f - bz * txy;
  const int by = r / tx;
  const int bx = r - by * tx;

  const int tid  = threadIdx.x;
  const int lane = tid & 63;
  const int wid  = tid >> 6;
  const int wr   = wid >> 2;              // 0..1 (M half)
  const int wc   = wid & 3;               // 0..3 (N quarter)
  const int lr   = lane & 15, lg = lane >> 4;

  // ---- ds_read lane bases: byte = base[kk] + imm ----
  // orig: row*128 + (((kk*4+lg)^(row&7))<<4), row = grp + lr, grp mult of 16
  //  ==>  [grpImm] + lr*128 + ((lg^(lr&3))<<4) + ((kk^((lr>>2)&1))<<6)
  const int xorlo = (lg ^ (lr & 3)) << 4;
  const int kb    = (lr >> 2) & 1;
  const int dsA0v = wr * 16384 + lr * 128 + xorlo + (kb << 6);
  const int dsA1v = wr * 16384 + lr * 128 + xorlo + ((1 ^ kb) << 6);
  const int dsB0v = 32768 + wc * 8192 + lr * 128 + xorlo + (kb << 6);
  const int dsB1v = 32768 + wc * 8192 + lr * 128 + xorlo + ((1 ^ kb) << 6);

  // ---- stage addressing: 2 advancing pointers + uniform offsets ----
  const int r7    = tid >> 3;                     // A row (alpha0,h0)
  const int pch   = tid & 7;
  const int rowB0 = (r7 & 31) | ((r7 & 32) << 1); // B row (beta0,h0)
  const long lda2 = lda * 2, ldb2 = ldb * 2;      // row stride in bytes
  const ushort_t* Abp = A + (long)bz * batchA + (long)by * 256 * lda;
  const ushort_t* Bbp = B + (long)bz * batchB + (long)bx * 256 * ldb;
  const char* gA = (const char*)(Abp + (long)r7 * lda + (pch ^ (r7 & 7)) * 8);
  const char* gB = (const char*)(Bbp + (long)rowB0 * ldb + (pch ^ (rowB0 & 7)) * 8);
  const int dA0 = r7 * 128 + pch * 16;            // LDS dest base (op A)
  const int dB0 = 32768 + rowB0 * 128 + pch * 16; // LDS dest base (op B)
  char* ldsc = (char*)&lds[0][0][0];

  // uniform per-variant source offsets (bytes): rowDelta*ld2 + tileDelta*128
  const long aP0 = 64 * lda2 + 128,  aP1 = 192 * lda2 + 128;   // alpha1 h0/h1 @t+1
  const long aP2 = 256,              aP2b = 128 * lda2 + 256;  // alpha0 h0/h1 @t+2
  const long bP0 = 32 * ldb2 + 128,  bP1 = 160 * ldb2 + 128;   // beta1  h0/h1 @t+1
  const long bP3 = 256,              bP3b = 128 * ldb2 + 256;  // beta0  h0/h1 @t+2

  f32x4 acc[8][4] = {};
  bf16x8 afr[2][2];   // current M-quarter fragments
  bf16x8 bfr[4][2];   // full-N fragments (held across the K-tile)

  auto gld = [&](const char* src, int dst) {
    __builtin_amdgcn_global_load_lds((const __attribute__((address_space(1))) void*)src,
                                     (__attribute__((address_space(3))) void*)(ldsc + dst),
                                     16, 0, 0);
  };
  auto readAq = [&](const char* lc, int q) {
#pragma unroll
    for (int mm = 0; mm < 2; ++mm) {
      afr[mm][0] = *(const bf16x8*)(lc + dsA0v + ((q * 2 + mm) << 11));
      afr[mm][1] = *(const bf16x8*)(lc + dsA1v + ((q * 2 + mm) << 11));
    }
  };
  auto readB = [&](const char* lc) {
#pragma unroll
    for (int nn = 0; nn < 4; ++nn) {
      bfr[nn][0] = *(const bf16x8*)(lc + dsB0v + (nn << 11));
      bfr[nn][1] = *(const bf16x8*)(lc + dsB1v + (nn << 11));
    }
  };
  auto mfma16q = [&](int q) {
    __builtin_amdgcn_s_setprio(1);
#pragma unroll
    for (int kk = 0; kk < 2; ++kk)
#pragma unroll
      for (int nn = 0; nn < 4; ++nn)
#pragma unroll
        for (int mm = 0; mm < 2; ++mm)
          acc[q * 2 + mm][nn] = __builtin_amdgcn_mfma_f32_16x16x32_bf16(
              afr[mm][kk], bfr[nn][kk], acc[q * 2 + mm][nn], 0, 0, 0);
    __builtin_amdgcn_s_setprio(0);
  };

  const int nkt = K >> 6;                 // >= 16 for all our shapes
  // prologue: tile0 full -> buf0 (first 8 issues), tile1 1st halves -> buf1
  gld(gA, dA0);                    gld(gA + 128 * lda2, dA0 + 16384);
  gld(gB, dB0);                    gld(gB + 128 * ldb2, dB0 + 16384);
  gld(gA + 64 * lda2, dA0 + 8192); gld(gA + 192 * lda2, dA0 + 24576);
  gld(gB + 32 * ldb2, dB0 + 4096); gld(gB + 160 * ldb2, dB0 + 20480);
  gld(gA + 128, 65536 + dA0);            gld(gA + 128 * lda2 + 128, 65536 + dA0 + 16384);
  gld(gB + 128, 65536 + dB0);            gld(gB + 128 * ldb2 + 128, 65536 + dB0 + 16384);
  WAITVM(4);                              // tile0's 8 loads landed
  BARRIER(); SCHED0();

  for (int t = 0; t < nkt - 2; ++t) {
    const int cb = t & 1;
    const char* lc = ldsc + (cb << 16);
    const int obo = (cb ^ 1) << 16, cbo = cb << 16;
    // PH0
    readAq(lc, 0); readB(lc);
    gld(gA + aP0, obo + dA0 + 8192);  gld(gB + bP0, obo + dB0 + 4096);
    mfma16q(0); BARRIER(); SCHED0();
    // PH1
    readAq(lc, 1);
    gld(gA + aP1, obo + dA0 + 24576); gld(gB + bP1, obo + dB0 + 20480);
    mfma16q(1); BARRIER(); SCHED0();
    // PH2
    readAq(lc, 2);
    gld(gA + aP2, cbo + dA0);         gld(gA + aP2b, cbo + dA0 + 16384);
    mfma16q(2); BARRIER(); SCHED0();
    // PH3
    readAq(lc, 3);
    gld(gB + bP3, cbo + dB0);         gld(gB + bP3b, cbo + dB0 + 16384);
    WAITVM(4); mfma16q(3); BARRIER(); SCHED0();
    gA += 128; gB += 128;                 // advance one K-tile (64 elem * 2B)
  }
  {                                       // t = nkt-2: stage tile nkt-1 2nd halves only
    const int cb = (nkt - 2) & 1;
    const char* lc = ldsc + (cb << 16);
    const int obo = (cb ^ 1) << 16;
    readAq(lc, 0); readB(lc);
    gld(gA + aP0, obo + dA0 + 8192);  gld(gB + bP0, obo + dB0 + 4096);
    mfma16q(0); BARRIER(); SCHED0();
    readAq(lc, 1);
    gld(gA + aP1, obo + dA0 + 24576); gld(gB + bP1, obo + dB0 + 20480);
    mfma16q(1); BARRIER(); SCHED0();
    readAq(lc, 2);
    mfma16q(2); BARRIER(); SCHED0();
    readAq(lc, 3);
    WAITVM(0);                            // drain: tile nkt-1 fully landed
    mfma16q(3); BARRIER(); SCHED0();
  }
  {                                       // t = nkt-1: pure compute, no hazards
    const int cb = (nkt - 1) & 1;
    const char* lc = ldsc + (cb << 16);
    readAq(lc, 0); readB(lc); mfma16q(0);
    readAq(lc, 1); mfma16q(1);
    readAq(lc, 2); mfma16q(2);
    readAq(lc, 3); mfma16q(3);
  }

  // epilogue: C/D frag layout col=lane&15, row=(lane>>4)*4+j
  const long Crow0 = (long)by * 256 + wr * 128;
  const long Ccol0 = (long)bx * 256 + wc * 64;
  float*     Cf = (float*)C + (long)bz * batchC;
  ushort_t*  Cb = (ushort_t*)C + (long)bz * batchC;
#pragma unroll
  for (int m = 0; m < 8; ++m) {
    long r0 = Crow0 + m * 16 + ((lane >> 4) << 2);
#pragma unroll
    for (int n = 0; n < 4; ++n) {
      long cc = Ccol0 + n * 16 + (lane & 15);
#pragma unroll
      for (int j = 0; j < 4; ++j) {
        float val = acc[m][n][j];
        if (OUT_BF16) Cb[(r0 + j) * ldc + cc] = f2bf(val);
        else          Cf[(r0 + j) * ldc + cc] = val;
      }
    }
  }
}

// ---------------------------------------------------------------------------
// row softmax over 4096 fp32 scores; write normalized P bf16 to P+row*pstride
__global__ __launch_bounds__(256) void softmax_kernel(float* __restrict__ S,
                                                      ushort_t* __restrict__ P,
                                                      long pstride) {
  float* row = S + (long)blockIdx.x * 4096;
  const int tid = threadIdx.x;
  __shared__ float red[4];

  f32x4 v[4];
#pragma unroll
  for (int i = 0; i < 4; ++i) v[i] = ((const f32x4*)row)[tid + i * 256];

  float m = -1e30f;
#pragma unroll
  for (int i = 0; i < 4; ++i)
#pragma unroll
    for (int j = 0; j < 4; ++j) m = fmaxf(m, v[i][j]);
  for (int o = 32; o; o >>= 1) m = fmaxf(m, __shfl_xor(m, o));
  if ((tid & 63) == 0) red[tid >> 6] = m;
  __syncthreads();
  m = fmaxf(fmaxf(red[0], red[1]), fmaxf(red[2], red[3]));

  float p[16];
  float s = 0.f;
#pragma unroll
  for (int i = 0; i < 4; ++i)
#pragma unroll
    for (int j = 0; j < 4; ++j) {
      float e = __expf(v[i][j] - m);
      p[i * 4 + j] = e;
      s += e;
    }
  for (int o = 32; o; o >>= 1) s += __shfl_xor(s, o);
  __syncthreads();
  if ((tid & 63) == 0) red[tid >> 6] = s;
  __syncthreads();
  s = red[0] + red[1] + red[2] + red[3];
  float inv = 1.0f / s;

  u16x4* prow = (u16x4*)(P + (long)blockIdx.x * pstride);
#pragma unroll
  for (int i = 0; i < 4; ++i) {
    u16x4 o;
    o.x = f2bf(p[i * 4 + 0] * inv);
    o.y = f2bf(p[i * 4 + 1] * inv);
    o.z = f2bf(p[i * 4 + 2] * inv);
    o.w = f2bf(p[i * 4 + 3] * inv);
    prow[tid + i * 256] = o;
  }
}

// row softmax over 4096 bf16 scores, P bf16 written IN PLACE (row-local)
__global__ __launch_bounds__(256) void softmax_bf16_kernel(ushort_t* __restrict__ S) {
  u16x4* row = (u16x4*)(S + (long)blockIdx.x * 4096);
  const int tid = threadIdx.x;
  __shared__ float red[4];

  float v[16];
#pragma unroll
  for (int i = 0; i < 4; ++i) {
    u16x4 h = row[tid + i * 256];
    v[i * 4 + 0] = bf2f(h.x); v[i * 4 + 1] = bf2f(h.y);
    v[i * 4 + 2] = bf2f(h.z); v[i * 4 + 3] = bf2f(h.w);
  }

  float m = -1e30f;
#pragma unroll
  for (int i = 0; i < 16; ++i) m = fmaxf(m, v[i]);
  for (int o = 32; o; o >>= 1) m = fmaxf(m, __shfl_xor(m, o));
  if ((tid & 63) == 0) red[tid >> 6] = m;
  __syncthreads();
  m = fmaxf(fmaxf(red[0], red[1]), fmaxf(red[2], red[3]));

  float s = 0.f;
#pragma unroll
  for (int i = 0; i < 16; ++i) {
    v[i] = __expf(v[i] - m);
    s += v[i];
  }
  for (int o = 32; o; o >>= 1) s += __shfl_xor(s, o);
  __syncthreads();
  if ((tid & 63) == 0) red[tid >> 6] = s;
  __syncthreads();
  s = red[0] + red[1] + red[2] + red[3];
  float inv = 1.0f / s;

#pragma unroll
  for (int i = 0; i < 4; ++i) {
    u16x4 o;
    o.x = f2bf(v[i * 4 + 0] * inv);
    o.y = f2bf(v[i * 4 + 1] * inv);
    o.z = f2bf(v[i * 4 + 2] * inv);
    o.w = f2bf(v[i * 4 + 3] * inv);
    row[tid + i * 256] = o;
  }
}

// ---------------------------------------------------------------------------
extern "C" void kernel_launch(void* const* d_in, const int* in_sizes, int n_in,
                              void* d_out, int out_size, void* d_ws, size_t ws_size,
                              hipStream_t stream) {
  const float* x    = (const float*)d_in[0];   // [4,4096,1024]
  const float* kern = (const float*)d_in[1];   // [3,1024,1024]
  float* out = (float*)d_out;                  // [4,4096,1024]

  char* p = (char*)d_ws;
  ushort_t* xbf = (ushort_t*)p; p += 33554432;         // 16384x1024 bf16
  ushort_t* t   = (ushort_t*)p; p += 33554432;         // 16384x1024 bf16
  ushort_t* vT  = (ushort_t*)p; p += 33554432;         // 4x1024x4096 bf16
  ushort_t* wk  = (ushort_t*)p; p += 2097152;
  ushort_t* wq  = (ushort_t*)p; p += 2097152;
  ushort_t* wvt = (ushort_t*)p; p += 2097152;
  ushort_t* mt  = (ushort_t*)p; p += 2097152;
  size_t fixed = (size_t)(p - (char*)d_ws);            // 104 MiB

  cast_bf16_kernel<<<8192, 256, 0, stream>>>(x, xbf);
  prep_weights_kernel<<<4096, 256, 0, stream>>>(kern, wk, wq, wvt);
  // Mt[d',d] = sum_e Wk[d',e] * Wq_s[d,e]  (tiny; 128^2 kernel)
  gemm_bt<1><<<dim3(8, 8, 1), 256, 0, stream>>>(wk, 1024, 0, wq, 1024, 0, mt, 1024, 0, 1024);

  const size_t need4 = fixed + 4ull * 33554432;        // 4 bf16 S/P buffers
  const size_t need2 = fixed + 2ull * 33554432;        // 2 bf16 S/P buffers

  if (ws_size >= need2) {
    ushort_t* Sb = (ushort_t*)p;                       // 2 or 4 x (4096x4096 bf16)

    // t[q,d'] = sum_d x[q,d] * Mt[d',d]      grid 4x64 = 256
    gemm256<1><<<dim3(256), dim3(512), 0, stream>>>(xbf, 1024, 0, mt, 1024, 0,
                                                    t, 1024, 0, 1024, 4, 64);
    // vT[b][e,s] = sum_d WvT[e,d] * x_b[s,d]  grid 16x4x4 = 256
    gemm256<1><<<dim3(256), dim3(512), 0, stream>>>(wvt, 1024, 0,
                                                    xbf, 1024, 4194304,
                                                    vT, 4096, 4194304, 1024, 16, 4);

    const int nb_at_once = (ws_size >= need4) ? 4 : 2;
    for (int b0 = 0; b0 < 4; b0 += nb_at_once) {
      // S_b[q,k] = sum_d' t_b[q,d'] x_b[k,d']  (bf16 out), batched dispatch
      gemm256<1><<<dim3(256 * nb_at_once), dim3(512), 0, stream>>>(
          t + (long)b0 * 4194304, 1024, 4194304,
          xbf + (long)b0 * 4194304, 1024, 4194304,
          Sb, 4096, 16777216, 1024, 16, 16);
      // softmax all staged rows in one dispatch (in-place bf16 P)
      softmax_bf16_kernel<<<4096 * nb_at_once, 256, 0, stream>>>(Sb);
      // out[b][q,e] = sum_k P_b[q,k] vT_b[e,k]
      gemm256<0><<<dim3(4 * 16 * nb_at_once), dim3(512), 0, stream>>>(
          Sb, 4096, 16777216,
          vT + (long)b0 * 4194304, 4096, 4194304,
          out + (long)b0 * 4194304, 1024, 4194304, 4096, 4, 16);
    }
  } else {
    // -------- low-ws fallback (chunked, in-place packed P) --------
    float* Sbuf = (float*)p;
    long CR = 4096;
    while (CR > 256 && fixed + (size_t)CR * 4096 * 4 > ws_size) CR >>= 1;

    gemm_bt<1><<<dim3(8, 128, 1), 256, 0, stream>>>(xbf, 1024, 0, mt, 1024, 0, t, 1024, 0, 1024);
    gemm_bt<1><<<dim3(32, 8, 4), 256, 0, stream>>>(wvt, 1024, 0,
                                                   xbf, 1024, 4194304,
                                                   vT, 4096, 4194304, 1024);
    for (int b = 0; b < 4; ++b) {
      const ushort_t* xb  = xbf + (long)b * 4194304;
      const ushort_t* vTb = vT  + (long)b * 4194304;
      for (long c0 = 0; c0 < 4096; c0 += CR) {
        const ushort_t* tb = t + ((long)b * 4096 + c0) * 1024;
        gemm_bt<0><<<dim3(32, CR / 128, 1), 256, 0, stream>>>(tb, 1024, 0, xb, 1024, 0,
                                                              Sbuf, 4096, 0, 1024);
        softmax_kernel<<<CR, 256, 0, stream>>>(Sbuf, (ushort_t*)Sbuf, 8192);
        gemm_bt<0><<<dim3(8, CR / 128, 1), 256, 0, stream>>>((const ushort_t*)Sbuf, 8192, 0,
                                                             vTb, 4096, 0,
                                                             out + ((long)b * 4096 + c0) * 1024, 1024, 0,
                                                             4096);
      }
    }
  }
}